// Round 1
// baseline (348.251 us; speedup 1.0000x reference)
//
#include <hip/hip_runtime.h>
#include <math.h>

// Problem constants (derived from in_sizes at launch where possible)
#define F_OUT 128
#define N_HEAD 4

// ---------------- workspace layout (byte offsets, all 16B-aligned) -----------
// cumw   : 4*128 f32        @ 0        (2048 B)
// b      : 4*128 f32        @ 2048     (2048 B)   b[i][c] = cumw[i][c]*a_src[i][c]
// reldot : NREL*4 f32       @ 4096     (pad 8192)
// srcdot : N*4 f32          @ 12288    (800000 B)
// counts : N int            @ 812288   (200000 B)
// cursor : N int            @ 1012288  (200000 B)
// offsets: (N+1) int        @ 1212288  (pad 200016 B)
// sEe    : E float4         @ 1412304  (9600000 B)
// sSR    : E int2           @ 11012304 (4800000 B)
#define WS_CUMW    0
#define WS_B       2048
#define WS_RELDOT  4096
#define WS_SRCDOT  12288
#define WS_COUNTS  812288
#define WS_CURSOR  1012288
#define WS_OFFSETS 1212288
#define WS_SEE     1412304
#define WS_SSR     11012304

// 1) cumulative scaling + fused a_src scale.  1 block x 128 threads.
__global__ void prep_kernel(const float* __restrict__ w, const float* __restrict__ a,
                            float* __restrict__ cumw, float* __restrict__ b) {
    int c = threadIdx.x;  // 0..127
    float cw = 1.0f;
    for (int i = 0; i < N_HEAD; ++i) {
        cumw[i * F_OUT + c] = cw;
        b[i * F_OUT + c] = cw * a[(i * 2 + 0) * F_OUT + c];  // a_src[i][c]
        if (i < N_HEAD - 1) cw *= w[i * F_OUT + c];
    }
}

// 2) reldot[r][i] = inputr[r] . a_dst[i]   grid=NREL, block=64 (one wave)
__global__ void reldot_kernel(const float* __restrict__ inputr, const float* __restrict__ a,
                              float* __restrict__ reldot) {
    int r = blockIdx.x;
    int lane = threadIdx.x;  // 0..63
    float x0 = inputr[r * F_OUT + lane];
    float x1 = inputr[r * F_OUT + lane + 64];
    float p[N_HEAD];
    #pragma unroll
    for (int i = 0; i < N_HEAD; ++i) {
        const float* ad = a + (i * 2 + 1) * F_OUT;  // a_dst[i]
        p[i] = x0 * ad[lane] + x1 * ad[lane + 64];
    }
    #pragma unroll
    for (int off = 32; off > 0; off >>= 1) {
        #pragma unroll
        for (int i = 0; i < N_HEAD; ++i) p[i] += __shfl_down(p[i], off);
    }
    if (lane == 0) {
        float4* o = (float4*)(reldot + r * 4);
        *o = make_float4(p[0], p[1], p[2], p[3]);
    }
}

// 3) srcdot[n][i] = h0[n] . b[i]   grid=N, block=64
__global__ void srcdot_kernel(const float* __restrict__ h, const float* __restrict__ b,
                              float* __restrict__ srcdot) {
    int n = blockIdx.x;
    int lane = threadIdx.x;
    float x0 = h[n * F_OUT + lane];
    float x1 = h[n * F_OUT + lane + 64];
    float p[N_HEAD];
    #pragma unroll
    for (int i = 0; i < N_HEAD; ++i) {
        const float* bi = b + i * F_OUT;
        p[i] = x0 * bi[lane] + x1 * bi[lane + 64];
    }
    #pragma unroll
    for (int off = 32; off > 0; off >>= 1) {
        #pragma unroll
        for (int i = 0; i < N_HEAD; ++i) p[i] += __shfl_down(p[i], off);
    }
    if (lane == 0) {
        float4* o = (float4*)(srcdot + n * 4);
        *o = make_float4(p[0], p[1], p[2], p[3]);
    }
}

// 4) histogram of dst
__global__ void hist_kernel(const int* __restrict__ A, int* __restrict__ counts, int E) {
    int e = blockIdx.x * blockDim.x + threadIdx.x;
    if (e >= E) return;
    atomicAdd(&counts[A[e]], 1);
}

// 5) exclusive scan of counts -> offsets.  Single block of 1024 threads.
__global__ void scan_kernel(const int* __restrict__ counts, int* __restrict__ offsets,
                            int N, int E) {
    __shared__ int sums[1024];
    int t = threadIdx.x;
    int CH = (N + 1023) / 1024;
    int begin = t * CH;
    int end = begin + CH; if (end > N) end = N;
    int s = 0;
    for (int j = begin; j < end; ++j) s += counts[j];
    sums[t] = s;
    __syncthreads();
    for (int off = 1; off < 1024; off <<= 1) {
        int v = (t >= off) ? sums[t - off] : 0;
        __syncthreads();
        sums[t] += v;
        __syncthreads();
    }
    int run = (t == 0) ? 0 : sums[t - 1];
    for (int j = begin; j < end; ++j) { offsets[j] = run; run += counts[j]; }
    if (t == 0) offsets[N] = E;
}

// 6) scatter edges into CSR order; compute edge_e for all 4 heads on the fly.
__global__ void scatter_kernel(const int* __restrict__ A,
                               const float* __restrict__ srcdot,
                               const float* __restrict__ reldot,
                               const int* __restrict__ offsets,
                               int* __restrict__ cursor,
                               int2* __restrict__ sSR,
                               float4* __restrict__ sEe, int E) {
    int e = blockIdx.x * blockDim.x + threadIdx.x;
    if (e >= E) return;
    int dst = A[e];
    int rel = A[E + e];
    int src = A[2 * E + e];
    float4 sd = *(const float4*)(srcdot + src * 4);
    float4 rd = *(const float4*)(reldot + rel * 4);
    float l[N_HEAD] = { sd.x + rd.x, sd.y + rd.y, sd.z + rd.z, sd.w + rd.w };
    float ee[N_HEAD];
    #pragma unroll
    for (int i = 0; i < N_HEAD; ++i) {
        float lr = (l[i] > 0.0f) ? l[i] : 0.2f * l[i];  // leaky_relu slope 0.2
        ee[i] = expf(-lr);
    }
    int pos = atomicAdd(&cursor[dst], 1);
    int idx = offsets[dst] + pos;
    sSR[idx] = make_int2(src, rel);
    sEe[idx] = make_float4(ee[0], ee[1], ee[2], ee[3]);
}

// 7) per-node accumulation.  grid=N, block=128 (thread = column).
__global__ void __launch_bounds__(128)
node_kernel(const float* __restrict__ h, const float* __restrict__ inputr,
            const float* __restrict__ cumw, const int* __restrict__ offsets,
            const int2* __restrict__ sSR, const float4* __restrict__ sEe,
            float* __restrict__ out, int N) {
    int n = blockIdx.x;
    int c = threadIdx.x;
    int s0 = offsets[n];
    int s1 = offsets[n + 1];
    float a1[N_HEAD] = {0, 0, 0, 0};
    float a2[N_HEAD] = {0, 0, 0, 0};
    float rs[N_HEAD] = {0, 0, 0, 0};
    for (int e = s0; e < s1; ++e) {
        float4 ee = sEe[e];
        int2 sr = sSR[e];
        float hc = h[sr.x * F_OUT + c];
        float rc = inputr[sr.y * F_OUT + c];
        a1[0] += hc * ee.x;  a2[0] += rc * ee.x;  rs[0] += ee.x;
        a1[1] += hc * ee.y;  a2[1] += rc * ee.y;  rs[1] += ee.y;
        a1[2] += hc * ee.z;  a2[2] += rc * ee.z;  rs[2] += ee.z;
        a1[3] += hc * ee.w;  a2[3] += rc * ee.w;  rs[3] += ee.w;
    }
    #pragma unroll
    for (int i = 0; i < N_HEAD; ++i) {
        out[((size_t)i * N + n) * F_OUT + c] = (cumw[i * F_OUT + c] * a1[i] - a2[i]) / rs[i];
    }
}

extern "C" void kernel_launch(void* const* d_in, const int* in_sizes, int n_in,
                              void* d_out, int out_size, void* d_ws, size_t ws_size,
                              hipStream_t stream) {
    const float* h      = (const float*)d_in[0];
    const float* inputr = (const float*)d_in[1];
    const float* w      = (const float*)d_in[2];
    const float* a      = (const float*)d_in[3];
    const int*   A      = (const int*)d_in[4];
    float* out = (float*)d_out;

    const int N    = in_sizes[0] / F_OUT;   // 50000
    const int NREL = in_sizes[1] / F_OUT;   // 500
    const int E    = in_sizes[4] / 3;       // 600000

    char* ws = (char*)d_ws;
    float* cumw    = (float*)(ws + WS_CUMW);
    float* b       = (float*)(ws + WS_B);
    float* reldot  = (float*)(ws + WS_RELDOT);
    float* srcdot  = (float*)(ws + WS_SRCDOT);
    int*   counts  = (int*)(ws + WS_COUNTS);
    int*   cursor  = (int*)(ws + WS_CURSOR);
    int*   offsets = (int*)(ws + WS_OFFSETS);
    float4* sEe    = (float4*)(ws + WS_SEE);
    int2*   sSR    = (int2*)(ws + WS_SSR);

    // zero counts + cursor (adjacent regions)
    hipMemsetAsync(counts, 0, 2 * (size_t)N * sizeof(int), stream);

    prep_kernel<<<1, 128, 0, stream>>>(w, a, cumw, b);
    reldot_kernel<<<NREL, 64, 0, stream>>>(inputr, a, reldot);
    srcdot_kernel<<<N, 64, 0, stream>>>(h, b, srcdot);
    hist_kernel<<<(E + 255) / 256, 256, 0, stream>>>(A, counts, E);
    scan_kernel<<<1, 1024, 0, stream>>>(counts, offsets, N, E);
    scatter_kernel<<<(E + 255) / 256, 256, 0, stream>>>(A, srcdot, reldot, offsets,
                                                        cursor, sSR, sEe, E);
    node_kernel<<<N, 128, 0, stream>>>(h, inputr, cumw, offsets, sSR, sEe, out, N);
}

// Round 2
// 258.403 us; speedup vs baseline: 1.3477x; 1.3477x over previous
//
#include <hip/hip_runtime.h>
#include <math.h>

#define F_OUT 128
#define N_HEAD 4
#define SCAN_CHUNK 2048

// ---------------- workspace layout (byte offsets, all 16B-aligned) -----------
#define WS_CUMW    0         // 4*128 f32   (2048 B)
#define WS_B       2048      // 4*128 f32   (2048 B)
#define WS_RELDOT  4096      // NREL*4 f32  (pad to 8192)
#define WS_SRCDOT  12288     // N*4 f32     (800000 B)
#define WS_COUNTS  812288    // N int       (200000 B)
#define WS_CURSOR  1012288   // N int       (200000 B)
#define WS_OFFSETS 1212288   // (N+1) int   (pad 200016 B)
#define WS_BSUM    1412304   // 128 int     (512 B)
#define WS_BBASE   1412816   // 128 int     (512 B)
#define WS_SEE     1413328   // E float4    (9600000 B)
#define WS_SPK     11013328  // E u32       (2400000 B)   packed (rel<<16)|src

// 1) cumulative scaling + fused a_src scale.  1 block x 128 threads.
__global__ void prep_kernel(const float* __restrict__ w, const float* __restrict__ a,
                            float* __restrict__ cumw, float* __restrict__ b) {
    int c = threadIdx.x;
    float cw = 1.0f;
    for (int i = 0; i < N_HEAD; ++i) {
        cumw[i * F_OUT + c] = cw;
        b[i * F_OUT + c] = cw * a[(i * 2 + 0) * F_OUT + c];
        if (i < N_HEAD - 1) cw *= w[i * F_OUT + c];
    }
}

// 2) reldot[r][i] = inputr[r] . a_dst[i]   grid=NREL, block=64
__global__ void reldot_kernel(const float* __restrict__ inputr, const float* __restrict__ a,
                              float* __restrict__ reldot) {
    int r = blockIdx.x;
    int lane = threadIdx.x;
    float x0 = inputr[r * F_OUT + lane];
    float x1 = inputr[r * F_OUT + lane + 64];
    float p[N_HEAD];
    #pragma unroll
    for (int i = 0; i < N_HEAD; ++i) {
        const float* ad = a + (i * 2 + 1) * F_OUT;
        p[i] = x0 * ad[lane] + x1 * ad[lane + 64];
    }
    #pragma unroll
    for (int off = 32; off > 0; off >>= 1) {
        #pragma unroll
        for (int i = 0; i < N_HEAD; ++i) p[i] += __shfl_down(p[i], off);
    }
    if (lane == 0) {
        *(float4*)(reldot + r * 4) = make_float4(p[0], p[1], p[2], p[3]);
    }
}

// 3) srcdot[n][i] = h0[n] . b[i]   grid=ceil(N/4), block=256 (wave per node)
__global__ __launch_bounds__(256) void srcdot_kernel(const float* __restrict__ h,
                                                     const float* __restrict__ b,
                                                     float* __restrict__ srcdot, int N) {
    int n = blockIdx.x * 4 + (threadIdx.x >> 6);
    if (n >= N) return;
    int lane = threadIdx.x & 63;
    float x0 = h[n * F_OUT + lane];
    float x1 = h[n * F_OUT + lane + 64];
    float p[N_HEAD];
    #pragma unroll
    for (int i = 0; i < N_HEAD; ++i) {
        const float* bi = b + i * F_OUT;
        p[i] = x0 * bi[lane] + x1 * bi[lane + 64];
    }
    #pragma unroll
    for (int off = 32; off > 0; off >>= 1) {
        #pragma unroll
        for (int i = 0; i < N_HEAD; ++i) p[i] += __shfl_down(p[i], off);
    }
    if (lane == 0) {
        *(float4*)(srcdot + n * 4) = make_float4(p[0], p[1], p[2], p[3]);
    }
}

// 4) histogram of dst
__global__ void hist_kernel(const int* __restrict__ A, int* __restrict__ counts, int E) {
    int e = blockIdx.x * blockDim.x + threadIdx.x;
    if (e >= E) return;
    atomicAdd(&counts[A[e]], 1);
}

// 5a) per-chunk sums (chunk = 2048 counts)
__global__ __launch_bounds__(256) void block_sum_kernel(const int* __restrict__ counts,
                                                        int* __restrict__ bsum, int N) {
    int blk = blockIdx.x, t = threadIdx.x;
    int base = blk * SCAN_CHUNK;
    int s = 0;
    #pragma unroll
    for (int k = 0; k < 8; ++k) {
        int idx = base + t + k * 256;
        if (idx < N) s += counts[idx];
    }
    #pragma unroll
    for (int off = 32; off > 0; off >>= 1) s += __shfl_down(s, off);
    __shared__ int red[4];
    if ((t & 63) == 0) red[t >> 6] = s;
    __syncthreads();
    if (t == 0) bsum[blk] = red[0] + red[1] + red[2] + red[3];
}

// 5b) scan the (<=64) chunk sums in one wave
__global__ void scan_partials_kernel(const int* __restrict__ bsum, int* __restrict__ bbase,
                                     int NB, int* __restrict__ offsets, int N, int E) {
    int t = threadIdx.x;  // 64 threads, one wave
    int orig = (t < NB) ? bsum[t] : 0;
    int v = orig;
    #pragma unroll
    for (int off = 1; off < 64; off <<= 1) {
        int u = __shfl_up(v, off);
        if (t >= off) v += u;
    }
    if (t < NB) bbase[t] = v - orig;  // exclusive
    if (t == 0) offsets[N] = E;
}

// 5c) per-chunk exclusive scan + write offsets
__global__ __launch_bounds__(256) void scan_write_kernel(const int* __restrict__ counts,
                                                         const int* __restrict__ bbase,
                                                         int* __restrict__ offsets, int N) {
    __shared__ int tsum[256];
    int blk = blockIdx.x, t = threadIdx.x;
    int base = blk * SCAN_CHUNK + t * 8;
    int v[8];
    #pragma unroll
    for (int k = 0; k < 8; ++k) {
        int idx = base + k;
        v[k] = (idx < N) ? counts[idx] : 0;
    }
    int s = 0;
    #pragma unroll
    for (int k = 0; k < 8; ++k) { int t0 = v[k]; v[k] = s; s += t0; }
    tsum[t] = s;
    __syncthreads();
    for (int off = 1; off < 256; off <<= 1) {
        int u = (t >= off) ? tsum[t - off] : 0;
        __syncthreads();
        tsum[t] += u;
        __syncthreads();
    }
    int tbase = bbase[blk] + ((t == 0) ? 0 : tsum[t - 1]);
    #pragma unroll
    for (int k = 0; k < 8; ++k) {
        int idx = base + k;
        if (idx < N) offsets[idx] = tbase + v[k];
    }
}

// 6) scatter edges into CSR order; compute edge_e for all 4 heads; pack (rel,src).
__global__ void scatter_kernel(const int* __restrict__ A,
                               const float* __restrict__ srcdot,
                               const float* __restrict__ reldot,
                               const int* __restrict__ offsets,
                               int* __restrict__ cursor,
                               unsigned* __restrict__ sPK,
                               float4* __restrict__ sEe, int E) {
    int e = blockIdx.x * blockDim.x + threadIdx.x;
    if (e >= E) return;
    int dst = A[e];
    int rel = A[E + e];
    int src = A[2 * E + e];
    float4 sd = *(const float4*)(srcdot + src * 4);
    float4 rd = *(const float4*)(reldot + rel * 4);
    float l[N_HEAD] = { sd.x + rd.x, sd.y + rd.y, sd.z + rd.z, sd.w + rd.w };
    float ee[N_HEAD];
    #pragma unroll
    for (int i = 0; i < N_HEAD; ++i) {
        float lr = (l[i] > 0.0f) ? l[i] : 0.2f * l[i];
        ee[i] = expf(-lr);
    }
    int pos = atomicAdd(&cursor[dst], 1);
    int idx = offsets[dst] + pos;
    sPK[idx] = ((unsigned)rel << 16) | (unsigned)src;
    sEe[idx] = make_float4(ee[0], ee[1], ee[2], ee[3]);
}

// 7) per-node accumulation, LDS-staged edge records.  grid=N, block=128.
#define STAGE 128
__global__ void __launch_bounds__(128)
node_kernel(const float* __restrict__ h, const float* __restrict__ inputr,
            const float* __restrict__ cumw, const int* __restrict__ offsets,
            const unsigned* __restrict__ sPK, const float4* __restrict__ sEe,
            float* __restrict__ out, int N) {
    __shared__ float4 see[STAGE];
    __shared__ unsigned spk[STAGE];
    int n = blockIdx.x;
    int c = threadIdx.x;
    int s0 = offsets[n];
    int s1 = offsets[n + 1];
    float a1[N_HEAD] = {0, 0, 0, 0};
    float a2[N_HEAD] = {0, 0, 0, 0};
    float rs[N_HEAD] = {0, 0, 0, 0};
    for (int base = s0; base < s1; base += STAGE) {
        int cnt = min(STAGE, s1 - base);
        if (c < cnt) {
            see[c] = sEe[base + c];
            spk[c] = sPK[base + c];
        }
        __syncthreads();
        #pragma unroll 4
        for (int j = 0; j < cnt; ++j) {
            float4 ee = see[j];
            unsigned pk = spk[j];
            float hc = h[(pk & 0xFFFFu) * F_OUT + c];
            float rc = inputr[(pk >> 16) * F_OUT + c];
            a1[0] += hc * ee.x;  a2[0] += rc * ee.x;  rs[0] += ee.x;
            a1[1] += hc * ee.y;  a2[1] += rc * ee.y;  rs[1] += ee.y;
            a1[2] += hc * ee.z;  a2[2] += rc * ee.z;  rs[2] += ee.z;
            a1[3] += hc * ee.w;  a2[3] += rc * ee.w;  rs[3] += ee.w;
        }
        __syncthreads();
    }
    #pragma unroll
    for (int i = 0; i < N_HEAD; ++i) {
        out[((size_t)i * N + n) * F_OUT + c] = (cumw[i * F_OUT + c] * a1[i] - a2[i]) / rs[i];
    }
}

extern "C" void kernel_launch(void* const* d_in, const int* in_sizes, int n_in,
                              void* d_out, int out_size, void* d_ws, size_t ws_size,
                              hipStream_t stream) {
    const float* h      = (const float*)d_in[0];
    const float* inputr = (const float*)d_in[1];
    const float* w      = (const float*)d_in[2];
    const float* a      = (const float*)d_in[3];
    const int*   A      = (const int*)d_in[4];
    float* out = (float*)d_out;

    const int N    = in_sizes[0] / F_OUT;   // 50000
    const int NREL = in_sizes[1] / F_OUT;   // 500
    const int E    = in_sizes[4] / 3;       // 600000
    const int NB   = (N + SCAN_CHUNK - 1) / SCAN_CHUNK;  // 25

    char* ws = (char*)d_ws;
    float*    cumw    = (float*)(ws + WS_CUMW);
    float*    b       = (float*)(ws + WS_B);
    float*    reldot  = (float*)(ws + WS_RELDOT);
    float*    srcdot  = (float*)(ws + WS_SRCDOT);
    int*      counts  = (int*)(ws + WS_COUNTS);
    int*      cursor  = (int*)(ws + WS_CURSOR);
    int*      offsets = (int*)(ws + WS_OFFSETS);
    int*      bsum    = (int*)(ws + WS_BSUM);
    int*      bbase   = (int*)(ws + WS_BBASE);
    float4*   sEe     = (float4*)(ws + WS_SEE);
    unsigned* sPK     = (unsigned*)(ws + WS_SPK);

    hipMemsetAsync(counts, 0, 2 * (size_t)N * sizeof(int), stream);  // counts + cursor

    prep_kernel<<<1, 128, 0, stream>>>(w, a, cumw, b);
    reldot_kernel<<<NREL, 64, 0, stream>>>(inputr, a, reldot);
    srcdot_kernel<<<(N + 3) / 4, 256, 0, stream>>>(h, b, srcdot, N);
    hist_kernel<<<(E + 255) / 256, 256, 0, stream>>>(A, counts, E);
    block_sum_kernel<<<NB, 256, 0, stream>>>(counts, bsum, N);
    scan_partials_kernel<<<1, 64, 0, stream>>>(bsum, bbase, NB, offsets, N, E);
    scan_write_kernel<<<NB, 256, 0, stream>>>(counts, bbase, offsets, N);
    scatter_kernel<<<(E + 255) / 256, 256, 0, stream>>>(A, srcdot, reldot, offsets,
                                                        cursor, sPK, sEe, E);
    node_kernel<<<N, 128, 0, stream>>>(h, inputr, cumw, offsets, sPK, sEe, out, N);
}